// Round 6
// baseline (248.689 us; speedup 1.0000x reference)
//
#include <hip/hip_runtime.h>
#include <hip/hip_bf16.h>
#include <stdint.h>

typedef unsigned short u16;
typedef unsigned int   u32;

#define HH 192
#define WW 192
#define HWSZ (192*192)
#define NPIX (2*HWSZ)
#define NTILE 1152          // 64-pixel tiles
#define TPB   144           // tiles per XCD band (NTILE/8)

typedef __attribute__((ext_vector_type(8))) short short8;
typedef __attribute__((ext_vector_type(4))) float floatx4;

__device__ __forceinline__ float bflo(u32 u){ union{u32 i; float f;} v; v.i = u<<16; return v.f; }
__device__ __forceinline__ float bfhi(u32 u){ union{u32 i; float f;} v; v.i = u & 0xffff0000u; return v.f; }
__device__ __forceinline__ float bf2f(u16 u){ union{u32 i; float f;} v; v.i = ((u32)u)<<16; return v.f; }
__device__ __forceinline__ u16 f2bf(float f){
    union{float f; u32 i;} v; v.f = f;
    u32 b = v.i;
    u32 r = b + 0x7fffu + ((b>>16)&1u);
    return (u16)(r>>16);
}
// packed f32x2 -> bf16x2 (v_cvt_pk_bf16_f32), RN-even same as f2bf
__device__ __forceinline__ u32 pkbf(float a, float b){
    __hip_bfloat162 h = __float22bfloat162_rn(make_float2(a, b));
    union { __hip_bfloat162 h; u32 u; } cv; cv.h = h; return cv.u;
}

// XCD band swizzle: round-robin dispatch => blk&7 is (assumed) XCD id;
// give each XCD a contiguous band of 144 tiles (24 image rows) -> L2-resident.
__device__ __forceinline__ int band_tile(int blk){ return (blk & 7)*TPB + (blk >> 3); }

// ---- dtype sniffer: is x fp32 (vs bf16)? ----
__device__ __forceinline__ int sniff_fp32(const void* x) {
    const u32* x32 = (const u32*)x;
    int l = threadIdx.x & 63;
    u32 v = x32[l*2];
    u32 e = (v >> 7) & 0xFFu;
    int vote = (e >= 0x60u && e <= 0x8Fu) ? 1 : 0;
    unsigned long long m = __ballot(vote);
    return (__popcll(m) < 40) ? 1 : 0;
}

__device__ __forceinline__ u16 pick16(const void* p, int i, int fp32) {
    return fp32 ? f2bf(((const float*)p)[i]) : ((const u16*)p)[i];
}
__device__ __forceinline__ float pickf(const void* p, int i, int fp32) {
    return fp32 ? ((const float*)p)[i] : bf2f(((const u16*)p)[i]);
}

// ---------------- K0: weight prep ----------------
// bfrag: B-fragments of w_main in MFMA lane order (bf16):
//   short8 index = ((k*2+kk)*4 + nt)*64 + lane ; element j
//   o = nt*16 + (lane&15), c = kk*32 + ((lane>>4)&3)*8 + j, src w_main[o][c][k]
// wf: field weights fp32 float4 per (c,tap): wf[(c*9+tap)*4 + {sin,cos,str,whole}]
//     biases wf[9216..9219] = {brot0, brot1, bstr, bwh}
__global__ __launch_bounds__(256) void k0_prep(const void* __restrict__ x,
                        const void* __restrict__ wm,
                        const void* __restrict__ wrot,
                        const void* __restrict__ brot,
                        const void* __restrict__ wstr,
                        const void* __restrict__ bstr,
                        const void* __restrict__ wwh,
                        const void* __restrict__ bwh,
                        u16* __restrict__ bfrag, float* __restrict__ wf) {
    int fp32 = sniff_fp32(x);
    int e = blockIdx.x*256 + threadIdx.x;
    if (e < 9*2*4*64*8) {
        int j    = e & 7;
        int lane = (e>>3) & 63;
        int nt   = (e>>9) & 3;
        int kk   = (e>>11) & 1;
        int k    = e>>12;
        int o = nt*16 + (lane & 15);
        int c = kk*32 + ((lane>>4)&3)*8 + j;
        bfrag[e] = pick16(wm, (o*64 + c)*9 + k, fp32);
    }
    if (e < 9216) {               // e = (c*9+tap)*4 + j
        int j   = e & 3;
        int rem = e >> 2;
        int tap = rem % 9;
        int c   = rem / 9;
        float s;
        if (j==0)      s = pickf(wrot, c*9 + tap, fp32);
        else if (j==1) s = pickf(wrot, (64+c)*9 + tap, fp32);
        else if (j==2) s = pickf(wstr, c*9 + tap, fp32);
        else           s = pickf(wwh,  c*9 + tap, fp32);
        wf[e] = s;
    }
    if (e < 4) {
        float bv;
        if (e==0)      bv = pickf(brot, 0, fp32);
        else if (e==1) bv = pickf(brot, 1, fp32);
        else if (e==2) bv = pickf(bstr, 0, fp32);
        else           bv = pickf(bwh,  0, fp32);
        wf[9216 + e] = bv;
    }
}

// ---------------- K1: NCHW -> NHWC transpose (to bf16) ----------------
// 1152 blocks, band-swizzled; block = 64 px; thread (g,p): 16 channels of pixel p.
__global__ __launch_bounds__(256) void k1_transpose(const void* __restrict__ x, u16* __restrict__ xt) {
    int fp32 = sniff_fp32(x);
    int t = threadIdx.x;
    int g = t >> 6, p = t & 63;
    int tile = band_tile(blockIdx.x);
    int gp = tile*64 + p;
    int b = gp / HWSZ, hw = gp % HWSZ;
    u32 v[8];
    if (fp32) {
        const float* src = (const float*)x + (size_t)(b*64 + g*16)*HWSZ + hw;
#pragma unroll
        for (int i = 0; i < 8; i++) {
            float a = src[(size_t)(2*i)*HWSZ];
            float c = src[(size_t)(2*i+1)*HWSZ];
            v[i] = pkbf(a, c);
        }
    } else {
        const u16* src = (const u16*)x + (size_t)(b*64 + g*16)*HWSZ + hw;
#pragma unroll
        for (int i = 0; i < 8; i++) {
            u32 a = src[(size_t)(2*i)*HWSZ];
            u32 c = src[(size_t)(2*i+1)*HWSZ];
            v[i] = a | (c<<16);
        }
    }
    uint4* dst = (uint4*)(xt + (size_t)gp*64 + g*16);
    dst[0] = make_uint4(v[0], v[1], v[2], v[3]);
    dst[1] = make_uint4(v[4], v[5], v[6], v[7]);
}

// ---------------- K2: field convs fp32 (low-VGPR body + band swizzle) ----------------
// block = 64 pixels; 4 waves x 16 channels; LDS 4-way reduce.
__global__ __launch_bounds__(256) void k2_fields(const void* __restrict__ x, const float* __restrict__ wf,
                          float4* __restrict__ fields) {
    __shared__ float4 red[256];
    int fp32 = sniff_fp32(x);
    int t = threadIdx.x;
    int q = t >> 6, p = t & 63;
    int gp0 = band_tile(blockIdx.x) * 64;
    int gp = gp0 + p;
    int b = gp / HWSZ, hw = gp % HWSZ;
    int h = hw / WW, w = hw % WW;
    float a0=0.f, a1=0.f, a2=0.f, a3=0.f;
    const float4* wf4 = (const float4*)wf;
    if (fp32) {
        const float* xf = (const float*)x;
#pragma unroll 2
        for (int c16 = 0; c16 < 16; c16++) {
            int c = q*16 + c16;
            size_t plane = (size_t)(b*64 + c)*HWSZ;
#pragma unroll
            for (int kh = 0; kh < 3; kh++) {
                int y = h + kh - 1;
                if ((unsigned)y >= (unsigned)HH) continue;
#pragma unroll
                for (int kw = 0; kw < 3; kw++) {
                    int xx = w + kw - 1;
                    if ((unsigned)xx >= (unsigned)WW) continue;
                    float v = xf[plane + (size_t)y*WW + xx];
                    float4 wv = wf4[c*9 + kh*3 + kw];
                    a0 = fmaf(v, wv.x, a0);
                    a1 = fmaf(v, wv.y, a1);
                    a2 = fmaf(v, wv.z, a2);
                    a3 = fmaf(v, wv.w, a3);
                }
            }
        }
    } else {
        const u16* xu = (const u16*)x;
#pragma unroll 2
        for (int c16 = 0; c16 < 16; c16++) {
            int c = q*16 + c16;
            size_t plane = (size_t)(b*64 + c)*HWSZ;
#pragma unroll
            for (int kh = 0; kh < 3; kh++) {
                int y = h + kh - 1;
                if ((unsigned)y >= (unsigned)HH) continue;
#pragma unroll
                for (int kw = 0; kw < 3; kw++) {
                    int xx = w + kw - 1;
                    if ((unsigned)xx >= (unsigned)WW) continue;
                    float v = bf2f(xu[plane + (size_t)y*WW + xx]);
                    float4 wv = wf4[c*9 + kh*3 + kw];
                    a0 = fmaf(v, wv.x, a0);
                    a1 = fmaf(v, wv.y, a1);
                    a2 = fmaf(v, wv.z, a2);
                    a3 = fmaf(v, wv.w, a3);
                }
            }
        }
    }
    red[t] = make_float4(a0, a1, a2, a3);
    __syncthreads();
    if (t < 64) {
        float4 r0 = red[t], r1 = red[t+64], r2 = red[t+128], r3 = red[t+192];
        float s0 = r0.x + r1.x + r2.x + r3.x;
        float s1 = r0.y + r1.y + r2.y + r3.y;
        float s2 = r0.z + r1.z + r2.z + r3.z;
        float s3 = r0.w + r1.w + r2.w + r3.w;
        float sr = s0 + wf[9216];
        float cr = s1 + wf[9217];
        float inv = 1.0f / sqrtf(sr*sr + cr*cr + 1e-6f);
        float r  = tanhf(s2 + wf[9218])*1.25f + 1.75f;
        float wrv = 1.0f + fmaxf(s3 + wf[9219], 0.0f);
        fields[gp0 + t] = make_float4(sr*inv, cr*inv, r*wrv, wrv);
    }
}

// ---------------- K3: sample + MFMA GEMM — barrier-free K-loop ----------------
// Wave w owns pixels [16w,16w+16) and ALL 64 outputs. Lane (quad,l15):
//   A-frag layout A[m=l15][k=quad*8+j]: samples pixel 16w+l15, channels quad*8..+7
//   (a0) and 32+quad*8..+7 (a1) -> blend lands directly in MFMA A-registers.
// No LDS / no __syncthreads in the tap loop; corners double-buffered in VGPRs.
__global__ __launch_bounds__(256) void k3_main(const void* __restrict__ xorig,
                                               const u16* __restrict__ xt,
                                               const float4* __restrict__ fields,
                                               const u16* __restrict__ bfrag,
                                               void* __restrict__ out) {
    __shared__ u16 cmat[64*72];   // epilogue transpose only

    int fp32 = sniff_fp32(xorig);
    int t = threadIdx.x;
    int pix0 = band_tile(blockIdx.x) * 64;
    int b   = pix0 / HWSZ;
    int hw0 = pix0 % HWSZ;

    int wv = t >> 6, lane = t & 63;
    int quad = lane >> 4, l15 = lane & 15;
    int pl = wv*16 + l15;                 // this lane's pixel (local)
    int hw = hw0 + pl;
    int h = hw / WW, w = hw % WW;
    float4 f = fields[pix0 + pl];
    float sn = f.x, cs = f.y, rwr = f.z, wr = f.w;
    const u16* xbase = xt + (size_t)b*HWSZ*64 + quad*8;   // channel base folded in

    floatx4 acc[4];
#pragma unroll
    for (int i=0;i<4;i++) acc[i] = (floatx4){0.f,0.f,0.f,0.f};
    const short8* bfr = (const short8*)bfrag;

    // corner data: [buf][corner(4)][half(2)] -> 8 uint4 per buf
    uint4 cr[2][8];
    float wg[2][4];

    auto coords_load = [&](int k, int buf) {
        int di = k/3 - 1;
        int dj = k%3 - 1;
        float bd0 = (float)di * rwr;
        float bd1 = (float)dj * wr;
        float py = (float)h + cs*bd0 + sn*bd1;
        float px = (float)w - sn*bd0 + cs*bd1;
        float y0f = floorf(py), x0f = floorf(px);
        float ty = py - y0f, tx = px - x0f;
        int y0 = (int)y0f, x0 = (int)x0f;
        int y1 = y0 + 1,   x1 = x0 + 1;
        float fy0 = ((unsigned)y0 < (unsigned)HH) ? 1.f : 0.f;
        float fy1 = ((unsigned)y1 < (unsigned)HH) ? 1.f : 0.f;
        float fx0 = ((unsigned)x0 < (unsigned)WW) ? 1.f : 0.f;
        float fx1 = ((unsigned)x1 < (unsigned)WW) ? 1.f : 0.f;
        int yc0 = min(max(y0,0),HH-1), yc1 = min(max(y1,0),HH-1);
        int xc0 = min(max(x0,0),WW-1), xc1 = min(max(x1,0),WW-1);
        wg[buf][0] = (1.f-ty)*(1.f-tx)*fy0*fx0;
        wg[buf][1] = (1.f-ty)*tx      *fy0*fx1;
        wg[buf][2] = ty      *(1.f-tx)*fy1*fx0;
        wg[buf][3] = ty      *tx      *fy1*fx1;
        const u16* p00 = xbase + (size_t)(yc0*WW + xc0)*64;
        const u16* p01 = xbase + (size_t)(yc0*WW + xc1)*64;
        const u16* p10 = xbase + (size_t)(yc1*WW + xc0)*64;
        const u16* p11 = xbase + (size_t)(yc1*WW + xc1)*64;
        cr[buf][0] = *(const uint4*)(p00);
        cr[buf][1] = *(const uint4*)(p00 + 32);
        cr[buf][2] = *(const uint4*)(p01);
        cr[buf][3] = *(const uint4*)(p01 + 32);
        cr[buf][4] = *(const uint4*)(p10);
        cr[buf][5] = *(const uint4*)(p10 + 32);
        cr[buf][6] = *(const uint4*)(p11);
        cr[buf][7] = *(const uint4*)(p11 + 32);
    };

    coords_load(0, 0);

#pragma unroll 1
    for (int k = 0; k < 9; k++) {
        int buf = k & 1;
        // blend this tap's corners into MFMA A-fragments (registers only)
        float w00 = wg[buf][0], w01 = wg[buf][1], w10 = wg[buf][2], w11 = wg[buf][3];
        u32 a0u[4], a1u[4];
        {
            const u32* c00 = (const u32*)&cr[buf][0];   // half0: [0..3], half1: [4..7]
            const u32* c01 = (const u32*)&cr[buf][2];
            const u32* c10 = (const u32*)&cr[buf][4];
            const u32* c11 = (const u32*)&cr[buf][6];
#pragma unroll
            for (int j = 0; j < 4; j++) {
                float s0 = w00*bflo(c00[j]) + w01*bflo(c01[j]) + w10*bflo(c10[j]) + w11*bflo(c11[j]);
                float s1 = w00*bfhi(c00[j]) + w01*bfhi(c01[j]) + w10*bfhi(c10[j]) + w11*bfhi(c11[j]);
                a0u[j] = pkbf(s0, s1);
                float t0 = w00*bflo(c00[j+4]) + w01*bflo(c01[j+4]) + w10*bflo(c10[j+4]) + w11*bflo(c11[j+4]);
                float t1 = w00*bfhi(c00[j+4]) + w01*bfhi(c01[j+4]) + w10*bfhi(c10[j+4]) + w11*bfhi(c11[j+4]);
                a1u[j] = pkbf(t0, t1);
            }
        }
        short8 a0 = *(short8*)a0u;
        short8 a1 = *(short8*)a1u;

        if (k < 8) coords_load(k+1, buf ^ 1);   // next tap's gathers in flight across MFMA

#pragma unroll
        for (int nt = 0; nt < 4; nt++) {
            short8 b0 = bfr[((k*2+0)*4 + nt)*64 + lane];
            short8 b1 = bfr[((k*2+1)*4 + nt)*64 + lane];
            acc[nt] = __builtin_amdgcn_mfma_f32_16x16x32_bf16(a0, b0, acc[nt], 0, 0, 0);
            acc[nt] = __builtin_amdgcn_mfma_f32_16x16x32_bf16(a1, b1, acc[nt], 0, 0, 0);
        }
    }

    // ---- epilogue: C[px= wv*16+quad*4+reg][out= nt*16+l15] -> LDS -> coalesced stores ----
#pragma unroll
    for (int nt = 0; nt < 4; nt++) {
        int o = nt*16 + l15;
#pragma unroll
        for (int rg = 0; rg < 4; rg++) {
            int pxi = wv*16 + quad*4 + rg;
            cmat[o*72 + pxi] = f2bf(acc[nt][rg]);
        }
    }
    __syncthreads();
    {
        int o = t >> 2, q2 = t & 3;
        const uint4* s = (const uint4*)&cmat[o*72 + q2*16];
        uint4 v0 = s[0], v1 = s[1];
        size_t base = (size_t)(b*64 + o)*HWSZ + hw0 + q2*16;
        if (fp32) {
            float4* df = (float4*)((float*)out + base);
            df[0] = make_float4(bflo(v0.x), bfhi(v0.x), bflo(v0.y), bfhi(v0.y));
            df[1] = make_float4(bflo(v0.z), bfhi(v0.z), bflo(v0.w), bfhi(v0.w));
            df[2] = make_float4(bflo(v1.x), bfhi(v1.x), bflo(v1.y), bfhi(v1.y));
            df[3] = make_float4(bflo(v1.z), bfhi(v1.z), bflo(v1.w), bfhi(v1.w));
        } else {
            uint4* du = (uint4*)((u16*)out + base);
            du[0] = v0; du[1] = v1;
        }
    }
}

extern "C" void kernel_launch(void* const* d_in, const int* in_sizes, int n_in,
                              void* d_out, int out_size, void* d_ws, size_t ws_size,
                              hipStream_t stream) {
    const void* x    = d_in[0];
    const void* wm   = d_in[1];
    const void* wrot = d_in[2];
    const void* brot = d_in[3];
    const void* wstr = d_in[4];
    const void* bstr = d_in[5];
    const void* wwh  = d_in[6];
    const void* bwh  = d_in[7];

    char* ws = (char*)d_ws;
    u16*    xt     = (u16*)   (ws);              // 9,437,184 B
    float4* fields = (float4*)(ws + 9437184);    // 1,179,648 B
    u16*    bfrag  = (u16*)   (ws + 10616832);   //    73,728 B
    float*  wf     = (float*) (ws + 10690560);   //    36,880 B (9220 floats)

    k0_prep     <<<dim3(144),   dim3(256), 0, stream>>>(x, wm, wrot, brot, wstr, bstr, wwh, bwh, bfrag, wf);
    k1_transpose<<<dim3(NTILE), dim3(256), 0, stream>>>(x, xt);
    k2_fields   <<<dim3(NTILE), dim3(256), 0, stream>>>(x, wf, fields);
    k3_main     <<<dim3(NTILE), dim3(256), 0, stream>>>(x, xt, (const float4*)fields, bfrag, d_out);
}

// Round 9
// 156.542 us; speedup vs baseline: 1.5886x; 1.5886x over previous
//
#include <hip/hip_runtime.h>
#include <hip/hip_bf16.h>
#include <stdint.h>

typedef unsigned short u16;
typedef unsigned int   u32;

#define HH 192
#define WW 192
#define HWSZ (192*192)
#define NPIX (2*HWSZ)
#define NTILE 1152          // 64-pixel tiles
#define TPB   144           // tiles per XCD band (NTILE/8)

typedef __attribute__((ext_vector_type(8))) short short8;
typedef __attribute__((ext_vector_type(4))) float floatx4;

__device__ __forceinline__ float bflo(u32 u){ union{u32 i; float f;} v; v.i = u<<16; return v.f; }
__device__ __forceinline__ float bfhi(u32 u){ union{u32 i; float f;} v; v.i = u & 0xffff0000u; return v.f; }
__device__ __forceinline__ float bf2f(u16 u){ union{u32 i; float f;} v; v.i = ((u32)u)<<16; return v.f; }
__device__ __forceinline__ u16 f2bf(float f){
    union{float f; u32 i;} v; v.f = f;
    u32 b = v.i;
    u32 r = b + 0x7fffu + ((b>>16)&1u);
    return (u16)(r>>16);
}
// packed f32x2 -> bf16x2 (v_cvt_pk_bf16_f32), RN-even same as f2bf
__device__ __forceinline__ u32 pkbf(float a, float b){
    __hip_bfloat162 h = __float22bfloat162_rn(make_float2(a, b));
    union { __hip_bfloat162 h; u32 u; } cv; cv.h = h; return cv.u;
}

// XCD band swizzle: round-robin dispatch => blk&7 is (assumed) XCD id;
// give each XCD a contiguous band of 144 tiles (24 image rows) -> L2-resident.
__device__ __forceinline__ int band_tile(int blk){ return (blk & 7)*TPB + (blk >> 3); }

// ---- dtype sniffer: is x fp32 (vs bf16)? ----
__device__ __forceinline__ int sniff_fp32(const void* x) {
    const u32* x32 = (const u32*)x;
    int l = threadIdx.x & 63;
    u32 v = x32[l*2];
    u32 e = (v >> 7) & 0xFFu;
    int vote = (e >= 0x60u && e <= 0x8Fu) ? 1 : 0;
    unsigned long long m = __ballot(vote);
    return (__popcll(m) < 40) ? 1 : 0;
}

__device__ __forceinline__ u16 pick16(const void* p, int i, int fp32) {
    return fp32 ? f2bf(((const float*)p)[i]) : ((const u16*)p)[i];
}
__device__ __forceinline__ float pickf(const void* p, int i, int fp32) {
    return fp32 ? ((const float*)p)[i] : bf2f(((const u16*)p)[i]);
}

// ---------------- K0: weight prep ----------------
__global__ __launch_bounds__(256) void k0_prep(const void* __restrict__ x,
                        const void* __restrict__ wm,
                        const void* __restrict__ wrot,
                        const void* __restrict__ brot,
                        const void* __restrict__ wstr,
                        const void* __restrict__ bstr,
                        const void* __restrict__ wwh,
                        const void* __restrict__ bwh,
                        u16* __restrict__ bfrag, float* __restrict__ wf) {
    int fp32 = sniff_fp32(x);
    int e = blockIdx.x*256 + threadIdx.x;
    if (e < 9*2*4*64*8) {
        int j    = e & 7;
        int lane = (e>>3) & 63;
        int wd   = (e>>9) & 3;
        int kk   = (e>>11) & 1;
        int k    = e>>12;
        int o = wd*16 + (lane & 15);
        int c = kk*32 + ((lane>>4)&3)*8 + j;
        bfrag[e] = pick16(wm, (o*64 + c)*9 + k, fp32);
    }
    if (e < 9216) {               // e = (c*9+tap)*4 + j
        int j   = e & 3;
        int rem = e >> 2;
        int tap = rem % 9;
        int c   = rem / 9;
        float s;
        if (j==0)      s = pickf(wrot, c*9 + tap, fp32);
        else if (j==1) s = pickf(wrot, (64+c)*9 + tap, fp32);
        else if (j==2) s = pickf(wstr, c*9 + tap, fp32);
        else           s = pickf(wwh,  c*9 + tap, fp32);
        wf[e] = s;
    }
    if (e < 4) {
        float bv;
        if (e==0)      bv = pickf(brot, 0, fp32);
        else if (e==1) bv = pickf(brot, 1, fp32);
        else if (e==2) bv = pickf(bstr, 0, fp32);
        else           bv = pickf(bwh,  0, fp32);
        wf[9216 + e] = bv;
    }
}

// ---------------- K1: NCHW -> NHWC transpose (to bf16) ----------------
__global__ __launch_bounds__(256) void k1_transpose(const void* __restrict__ x, u16* __restrict__ xt) {
    int fp32 = sniff_fp32(x);
    int t = threadIdx.x;
    int g = t >> 6, p = t & 63;
    int tile = band_tile(blockIdx.x);
    int gp = tile*64 + p;
    int b = gp / HWSZ, hw = gp % HWSZ;
    u32 v[8];
    if (fp32) {
        const float* src = (const float*)x + (size_t)(b*64 + g*16)*HWSZ + hw;
#pragma unroll
        for (int i = 0; i < 8; i++) {
            float a = src[(size_t)(2*i)*HWSZ];
            float c = src[(size_t)(2*i+1)*HWSZ];
            v[i] = pkbf(a, c);
        }
    } else {
        const u16* src = (const u16*)x + (size_t)(b*64 + g*16)*HWSZ + hw;
#pragma unroll
        for (int i = 0; i < 8; i++) {
            u32 a = src[(size_t)(2*i)*HWSZ];
            u32 c = src[(size_t)(2*i+1)*HWSZ];
            v[i] = a | (c<<16);
        }
    }
    uint4* dst = (uint4*)(xt + (size_t)gp*64 + g*16);
    dst[0] = make_uint4(v[0], v[1], v[2], v[3]);
    dst[1] = make_uint4(v[4], v[5], v[6], v[7]);
}

// ---------------- K2: field convs fp32 — 8 waves x 8 channels, LDS 8-way reduce ----------------
__global__ __launch_bounds__(512) void k2_fields(const void* __restrict__ x, const float* __restrict__ wf,
                          float4* __restrict__ fields) {
    __shared__ float4 red[512];
    int fp32 = sniff_fp32(x);
    int t = threadIdx.x;
    int q = t >> 6, p = t & 63;       // q in 0..7: 8 channels each
    int gp0 = band_tile(blockIdx.x) * 64;
    int gp = gp0 + p;
    int b = gp / HWSZ, hw = gp % HWSZ;
    int h = hw / WW, w = hw % WW;
    float a0=0.f, a1=0.f, a2=0.f, a3=0.f;
    const float4* wf4 = (const float4*)wf;
    if (fp32) {
        const float* xf = (const float*)x;
#pragma unroll 2
        for (int c8 = 0; c8 < 8; c8++) {
            int c = q*8 + c8;
            size_t plane = (size_t)(b*64 + c)*HWSZ;
#pragma unroll
            for (int kh = 0; kh < 3; kh++) {
                int y = h + kh - 1;
                if ((unsigned)y >= (unsigned)HH) continue;
#pragma unroll
                for (int kw = 0; kw < 3; kw++) {
                    int xx = w + kw - 1;
                    if ((unsigned)xx >= (unsigned)WW) continue;
                    float v = xf[plane + (size_t)y*WW + xx];
                    float4 wv = wf4[c*9 + kh*3 + kw];
                    a0 = fmaf(v, wv.x, a0);
                    a1 = fmaf(v, wv.y, a1);
                    a2 = fmaf(v, wv.z, a2);
                    a3 = fmaf(v, wv.w, a3);
                }
            }
        }
    } else {
        const u16* xu = (const u16*)x;
#pragma unroll 2
        for (int c8 = 0; c8 < 8; c8++) {
            int c = q*8 + c8;
            size_t plane = (size_t)(b*64 + c)*HWSZ;
#pragma unroll
            for (int kh = 0; kh < 3; kh++) {
                int y = h + kh - 1;
                if ((unsigned)y >= (unsigned)HH) continue;
#pragma unroll
                for (int kw = 0; kw < 3; kw++) {
                    int xx = w + kw - 1;
                    if ((unsigned)xx >= (unsigned)WW) continue;
                    float v = bf2f(xu[plane + (size_t)y*WW + xx]);
                    float4 wv = wf4[c*9 + kh*3 + kw];
                    a0 = fmaf(v, wv.x, a0);
                    a1 = fmaf(v, wv.y, a1);
                    a2 = fmaf(v, wv.z, a2);
                    a3 = fmaf(v, wv.w, a3);
                }
            }
        }
    }
    red[t] = make_float4(a0, a1, a2, a3);
    __syncthreads();
    if (t < 64) {
        float s0 = 0.f, s1 = 0.f, s2 = 0.f, s3 = 0.f;
#pragma unroll
        for (int j = 0; j < 8; j++) {
            float4 r = red[t + 64*j];
            s0 += r.x; s1 += r.y; s2 += r.z; s3 += r.w;
        }
        float sr = s0 + wf[9216];
        float cr = s1 + wf[9217];
        float inv = 1.0f / sqrtf(sr*sr + cr*cr + 1e-6f);
        float r  = tanhf(s2 + wf[9218])*1.25f + 1.75f;
        float wrv = 1.0f + fmaxf(s3 + wf[9219], 0.0f);
        fields[gp0 + t] = make_float4(sr*inv, cr*inv, r*wrv, wrv);
    }
}

// ---------------- K3: sample + MFMA GEMM, double-buffered LDS, band swizzle ----------------
// (verbatim round-4 submission k3 — last fully-passing fast version, 152 us total)
__device__ __forceinline__ void load16(const u16* base, u32 r[8]) {
    const uint4* p = (const uint4*)base;
    uint4 a = p[0], b = p[1];
    r[0]=a.x; r[1]=a.y; r[2]=a.z; r[3]=a.w;
    r[4]=b.x; r[5]=b.y; r[6]=b.z; r[7]=b.w;
}

__global__ __launch_bounds__(256) void k3_main(const void* __restrict__ xorig,
                                               const u16* __restrict__ xt,
                                               const float4* __restrict__ fields,
                                               const u16* __restrict__ bfrag,
                                               void* __restrict__ out) {
    __shared__ u16 samp[2][64*72];   // double buffer: 64 px x 64 ch, rows padded to 72

    int fp32 = sniff_fp32(xorig);
    int t = threadIdx.x;
    int pix0 = band_tile(blockIdx.x) * 64;
    int b   = pix0 / HWSZ;
    int hw0 = pix0 % HWSZ;

    // sampling role
    int p = t >> 2, q = t & 3;            // pixel in tile, 16-ch chunk
    int hw = hw0 + p;
    int h = hw / WW, w = hw % WW;
    float4 f = fields[pix0 + p];
    float sn = f.x, cs = f.y, rwr = f.z, wr = f.w;
    const u16* xbase = xt + (size_t)b*HWSZ*64;

    // mfma role
    int wd = t >> 6, lane = t & 63;
    int quad = lane >> 4, l15 = lane & 15;
    floatx4 acc[4];
#pragma unroll
    for (int i=0;i<4;i++) acc[i] = (floatx4){0.f,0.f,0.f,0.f};
    const short8* bfr = (const short8*)bfrag;

    u32 r00[8], r01[8], r10[8], r11[8];
    float w00, w01, w10, w11;

    auto coords_load = [&](int k) {
        int di = k/3 - 1;
        int dj = k%3 - 1;
        float bd0 = (float)di * rwr;
        float bd1 = (float)dj * wr;
        float py = (float)h + cs*bd0 + sn*bd1;
        float px = (float)w - sn*bd0 + cs*bd1;
        float y0f = floorf(py), x0f = floorf(px);
        float ty = py - y0f, tx = px - x0f;
        int y0 = (int)y0f, x0 = (int)x0f;
        int y1 = y0 + 1,   x1 = x0 + 1;
        float fy0 = ((unsigned)y0 < (unsigned)HH) ? 1.f : 0.f;
        float fy1 = ((unsigned)y1 < (unsigned)HH) ? 1.f : 0.f;
        float fx0 = ((unsigned)x0 < (unsigned)WW) ? 1.f : 0.f;
        float fx1 = ((unsigned)x1 < (unsigned)WW) ? 1.f : 0.f;
        int yc0 = min(max(y0,0),HH-1), yc1 = min(max(y1,0),HH-1);
        int xc0 = min(max(x0,0),WW-1), xc1 = min(max(x1,0),WW-1);
        w00 = (1.f-ty)*(1.f-tx)*fy0*fx0;
        w01 = (1.f-ty)*tx      *fy0*fx1;
        w10 = ty      *(1.f-tx)*fy1*fx0;
        w11 = ty      *tx      *fy1*fx1;
        const u16* row0 = xbase + (size_t)(yc0*WW)*64 + q*16;
        const u16* row1 = xbase + (size_t)(yc1*WW)*64 + q*16;
        load16(row0 + xc0*64, r00);
        load16(row0 + xc1*64, r01);
        load16(row1 + xc0*64, r10);
        load16(row1 + xc1*64, r11);
    };

    auto blend_store = [&](int buf) {
        u32 packed[8];
#pragma unroll
        for (int d=0; d<8; d++) {
            float s0 = w00*bflo(r00[d]) + w01*bflo(r01[d]) + w10*bflo(r10[d]) + w11*bflo(r11[d]);
            float s1 = w00*bfhi(r00[d]) + w01*bfhi(r01[d]) + w10*bfhi(r10[d]) + w11*bfhi(r11[d]);
            packed[d] = pkbf(s0, s1);
        }
        uint4* dst = (uint4*)&samp[buf][p*72 + q*16];
        dst[0] = make_uint4(packed[0],packed[1],packed[2],packed[3]);
        dst[1] = make_uint4(packed[4],packed[5],packed[6],packed[7]);
    };

    coords_load(0);
    blend_store(0);

#pragma unroll 1
    for (int k = 0; k < 9; k++) {
        __syncthreads();
        if (k < 8) coords_load(k+1);          // gathers in flight across MFMA phase
        short8 b0 = bfr[((k*2+0)*4 + wd)*64 + lane];
        short8 b1 = bfr[((k*2+1)*4 + wd)*64 + lane];
        const u16* sb = samp[k & 1];
#pragma unroll
        for (int mt=0; mt<4; mt++) {
            int pr = mt*16 + l15;
            short8 a0 = *(const short8*)&sb[pr*72 +      quad*8];
            short8 a1 = *(const short8*)&sb[pr*72 + 32 + quad*8];
            acc[mt] = __builtin_amdgcn_mfma_f32_16x16x32_bf16(a0, b0, acc[mt], 0, 0, 0);
            acc[mt] = __builtin_amdgcn_mfma_f32_16x16x32_bf16(a1, b1, acc[mt], 0, 0, 0);
        }
        if (k < 8) blend_store((k+1) & 1);
    }
    __syncthreads();   // tap 8 read samp[0]; epilogue reuses it

    // ---- epilogue: transpose acc through LDS, coalesced stores ----
    {
        int o = wd*16 + l15;
#pragma unroll
        for (int mt=0; mt<4; mt++)
#pragma unroll
            for (int rg=0; rg<4; rg++) {
                int pxi = mt*16 + quad*4 + rg;
                samp[0][o*72 + pxi] = f2bf(acc[mt][rg]);
            }
    }
    __syncthreads();
    {
        int o = t >> 2, q2 = t & 3;
        const uint4* s = (const uint4*)&samp[0][o*72 + q2*16];
        uint4 v0 = s[0], v1 = s[1];
        size_t base = (size_t)(b*64 + o)*HWSZ + hw0 + q2*16;
        if (fp32) {
            float4* df = (float4*)((float*)out + base);
            df[0] = make_float4(bflo(v0.x), bfhi(v0.x), bflo(v0.y), bfhi(v0.y));
            df[1] = make_float4(bflo(v0.z), bfhi(v0.z), bflo(v0.w), bfhi(v0.w));
            df[2] = make_float4(bflo(v1.x), bfhi(v1.x), bflo(v1.y), bfhi(v1.y));
            df[3] = make_float4(bflo(v1.z), bfhi(v1.z), bflo(v1.w), bfhi(v1.w));
        } else {
            uint4* du = (uint4*)((u16*)out + base);
            du[0] = v0; du[1] = v1;
        }
    }
}

extern "C" void kernel_launch(void* const* d_in, const int* in_sizes, int n_in,
                              void* d_out, int out_size, void* d_ws, size_t ws_size,
                              hipStream_t stream) {
    const void* x    = d_in[0];
    const void* wm   = d_in[1];
    const void* wrot = d_in[2];
    const void* brot = d_in[3];
    const void* wstr = d_in[4];
    const void* bstr = d_in[5];
    const void* wwh  = d_in[6];
    const void* bwh  = d_in[7];

    char* ws = (char*)d_ws;
    u16*    xt     = (u16*)   (ws);              // 9,437,184 B
    float4* fields = (float4*)(ws + 9437184);    // 1,179,648 B
    u16*    bfrag  = (u16*)   (ws + 10616832);   //    73,728 B
    float*  wf     = (float*) (ws + 10690560);   //    36,880 B (9220 floats)

    k0_prep     <<<dim3(144),   dim3(256), 0, stream>>>(x, wm, wrot, brot, wstr, bstr, wwh, bwh, bfrag, wf);
    k1_transpose<<<dim3(NTILE), dim3(256), 0, stream>>>(x, xt);
    k2_fields   <<<dim3(NTILE), dim3(512), 0, stream>>>(x, wf, fields);
    k3_main     <<<dim3(NTILE), dim3(256), 0, stream>>>(x, xt, (const float4*)fields, bfrag, d_out);
}

// Round 10
// 151.758 us; speedup vs baseline: 1.6387x; 1.0315x over previous
//
#include <hip/hip_runtime.h>
#include <hip/hip_bf16.h>
#include <stdint.h>

typedef unsigned short u16;
typedef unsigned int   u32;

#define HH 192
#define WW 192
#define HWSZ (192*192)
#define NPIX (2*HWSZ)
#define NTILE 1152          // 64-pixel tiles
#define TPB   144           // tiles per XCD band (NTILE/8)

typedef __attribute__((ext_vector_type(8))) short short8;
typedef __attribute__((ext_vector_type(4))) float floatx4;

__device__ __forceinline__ float bflo(u32 u){ union{u32 i; float f;} v; v.i = u<<16; return v.f; }
__device__ __forceinline__ float bfhi(u32 u){ union{u32 i; float f;} v; v.i = u & 0xffff0000u; return v.f; }
__device__ __forceinline__ float bf2f(u16 u){ union{u32 i; float f;} v; v.i = ((u32)u)<<16; return v.f; }
__device__ __forceinline__ u16 f2bf(float f){
    union{float f; u32 i;} v; v.f = f;
    u32 b = v.i;
    u32 r = b + 0x7fffu + ((b>>16)&1u);
    return (u16)(r>>16);
}
// packed f32x2 -> bf16x2 (v_cvt_pk_bf16_f32), RN-even same as f2bf
__device__ __forceinline__ u32 pkbf(float a, float b){
    __hip_bfloat162 h = __float22bfloat162_rn(make_float2(a, b));
    union { __hip_bfloat162 h; u32 u; } cv; cv.h = h; return cv.u;
}

// XCD band swizzle: round-robin dispatch => blk&7 is (assumed) XCD id;
// each XCD owns a contiguous band of 144 tiles (24 image rows) -> L2-resident.
__device__ __forceinline__ int band_tile(int blk){ return (blk & 7)*TPB + (blk >> 3); }

// ---- dtype sniffer: is x fp32 (vs bf16)? ----
__device__ __forceinline__ int sniff_fp32(const void* x) {
    const u32* x32 = (const u32*)x;
    int l = threadIdx.x & 63;
    u32 v = x32[l*2];
    u32 e = (v >> 7) & 0xFFu;
    int vote = (e >= 0x60u && e <= 0x8Fu) ? 1 : 0;
    unsigned long long m = __ballot(vote);
    return (__popcll(m) < 40) ? 1 : 0;
}

__device__ __forceinline__ u16 pick16(const void* p, int i, int fp32) {
    return fp32 ? f2bf(((const float*)p)[i]) : ((const u16*)p)[i];
}
__device__ __forceinline__ float pickf(const void* p, int i, int fp32) {
    return fp32 ? ((const float*)p)[i] : bf2f(((const u16*)p)[i]);
}

// ---------------- K0: weight prep ----------------
__global__ __launch_bounds__(256) void k0_prep(const void* __restrict__ x,
                        const void* __restrict__ wm,
                        const void* __restrict__ wrot,
                        const void* __restrict__ brot,
                        const void* __restrict__ wstr,
                        const void* __restrict__ bstr,
                        const void* __restrict__ wwh,
                        const void* __restrict__ bwh,
                        u16* __restrict__ bfrag, float* __restrict__ wf) {
    int fp32 = sniff_fp32(x);
    int e = blockIdx.x*256 + threadIdx.x;
    if (e < 9*2*4*64*8) {
        int j    = e & 7;
        int lane = (e>>3) & 63;
        int wd   = (e>>9) & 3;
        int kk   = (e>>11) & 1;
        int k    = e>>12;
        int o = wd*16 + (lane & 15);
        int c = kk*32 + ((lane>>4)&3)*8 + j;
        bfrag[e] = pick16(wm, (o*64 + c)*9 + k, fp32);
    }
    if (e < 9216) {               // e = (c*9+tap)*4 + j
        int j   = e & 3;
        int rem = e >> 2;
        int tap = rem % 9;
        int c   = rem / 9;
        float s;
        if (j==0)      s = pickf(wrot, c*9 + tap, fp32);
        else if (j==1) s = pickf(wrot, (64+c)*9 + tap, fp32);
        else if (j==2) s = pickf(wstr, c*9 + tap, fp32);
        else           s = pickf(wwh,  c*9 + tap, fp32);
        wf[e] = s;
    }
    if (e < 4) {
        float bv;
        if (e==0)      bv = pickf(brot, 0, fp32);
        else if (e==1) bv = pickf(brot, 1, fp32);
        else if (e==2) bv = pickf(bstr, 0, fp32);
        else           bv = pickf(bwh,  0, fp32);
        wf[9216 + e] = bv;
    }
}

// ---------------- K12: FUSED transpose + field convs ----------------
// 512 threads: wave q (0..7) covers channels q*8..q*8+7 of its 64-pixel tile.
// The 3x3 stencil accumulates the 4 field convs (fp32); the center tap is
// re-read (L1-hit) and packed to bf16 -> one uint4 xt write per thread.
// Everything fully unrolled: all register indices compile-time (no scratch).
__global__ __launch_bounds__(512) void k12_fused(const void* __restrict__ x, const float* __restrict__ wf,
                          u16* __restrict__ xt, float4* __restrict__ fields) {
    __shared__ float4 red[512];
    int fp32 = sniff_fp32(x);
    int t = threadIdx.x;
    int q = t >> 6, p = t & 63;       // q: 8-channel group
    int gp0 = band_tile(blockIdx.x) * 64;
    int gp = gp0 + p;
    int b = gp / HWSZ, hw = gp % HWSZ;
    int h = hw / WW, w = hw % WW;
    float a0=0.f, a1=0.f, a2=0.f, a3=0.f;
    u32 xtv0, xtv1, xtv2, xtv3;
    const float4* wf4 = (const float4*)wf;
    if (fp32) {
        const float* xf = (const float*)x;
        float vc[8];
#pragma unroll
        for (int c8 = 0; c8 < 8; c8++) {
            int c = q*8 + c8;
            size_t plane = (size_t)(b*64 + c)*HWSZ;
#pragma unroll
            for (int kh = 0; kh < 3; kh++) {
                int y = h + kh - 1;
                if ((unsigned)y >= (unsigned)HH) continue;
#pragma unroll
                for (int kw = 0; kw < 3; kw++) {
                    int xx = w + kw - 1;
                    if ((unsigned)xx >= (unsigned)WW) continue;
                    float v = xf[plane + (size_t)y*WW + xx];
                    float4 wv = wf4[c*9 + kh*3 + kw];
                    a0 = fmaf(v, wv.x, a0);
                    a1 = fmaf(v, wv.y, a1);
                    a2 = fmaf(v, wv.z, a2);
                    a3 = fmaf(v, wv.w, a3);
                }
            }
            vc[c8] = xf[plane + (size_t)h*WW + w];   // center tap (always in-range, L1-hit)
        }
        xtv0 = pkbf(vc[0], vc[1]);
        xtv1 = pkbf(vc[2], vc[3]);
        xtv2 = pkbf(vc[4], vc[5]);
        xtv3 = pkbf(vc[6], vc[7]);
    } else {
        const u16* xu = (const u16*)x;
        u32 vc[8];
#pragma unroll
        for (int c8 = 0; c8 < 8; c8++) {
            int c = q*8 + c8;
            size_t plane = (size_t)(b*64 + c)*HWSZ;
#pragma unroll
            for (int kh = 0; kh < 3; kh++) {
                int y = h + kh - 1;
                if ((unsigned)y >= (unsigned)HH) continue;
#pragma unroll
                for (int kw = 0; kw < 3; kw++) {
                    int xx = w + kw - 1;
                    if ((unsigned)xx >= (unsigned)WW) continue;
                    float v = bf2f(xu[plane + (size_t)y*WW + xx]);
                    float4 wv = wf4[c*9 + kh*3 + kw];
                    a0 = fmaf(v, wv.x, a0);
                    a1 = fmaf(v, wv.y, a1);
                    a2 = fmaf(v, wv.z, a2);
                    a3 = fmaf(v, wv.w, a3);
                }
            }
            vc[c8] = xu[plane + (size_t)h*WW + w];
        }
        xtv0 = vc[0] | (vc[1]<<16);
        xtv1 = vc[2] | (vc[3]<<16);
        xtv2 = vc[4] | (vc[5]<<16);
        xtv3 = vc[6] | (vc[7]<<16);
    }
    // xt write: 8 channels (16 B) of pixel gp
    *(uint4*)(xt + (size_t)gp*64 + q*8) = make_uint4(xtv0, xtv1, xtv2, xtv3);

    // fields reduce: 512 -> 64
    red[t] = make_float4(a0, a1, a2, a3);
    __syncthreads();
    if (t < 64) {
        float s0 = 0.f, s1 = 0.f, s2 = 0.f, s3 = 0.f;
#pragma unroll
        for (int j = 0; j < 8; j++) {
            float4 r = red[t + 64*j];
            s0 += r.x; s1 += r.y; s2 += r.z; s3 += r.w;
        }
        float sr = s0 + wf[9216];
        float cr = s1 + wf[9217];
        float inv = 1.0f / sqrtf(sr*sr + cr*cr + 1e-6f);
        float r  = tanhf(s2 + wf[9218])*1.25f + 1.75f;
        float wrv = 1.0f + fmaxf(s3 + wf[9219], 0.0f);
        fields[gp0 + t] = make_float4(sr*inv, cr*inv, r*wrv, wrv);
    }
}

// ---------------- K3: sample + MFMA GEMM, double-buffered LDS, band swizzle ----------------
// (proven version — unchanged)
__device__ __forceinline__ void load16(const u16* base, u32 r[8]) {
    const uint4* p = (const uint4*)base;
    uint4 a = p[0], b = p[1];
    r[0]=a.x; r[1]=a.y; r[2]=a.z; r[3]=a.w;
    r[4]=b.x; r[5]=b.y; r[6]=b.z; r[7]=b.w;
}

__global__ __launch_bounds__(256) void k3_main(const void* __restrict__ xorig,
                                               const u16* __restrict__ xt,
                                               const float4* __restrict__ fields,
                                               const u16* __restrict__ bfrag,
                                               void* __restrict__ out) {
    __shared__ u16 samp[2][64*72];   // double buffer: 64 px x 64 ch, rows padded to 72

    int fp32 = sniff_fp32(xorig);
    int t = threadIdx.x;
    int pix0 = band_tile(blockIdx.x) * 64;
    int b   = pix0 / HWSZ;
    int hw0 = pix0 % HWSZ;

    // sampling role
    int p = t >> 2, q = t & 3;            // pixel in tile, 16-ch chunk
    int hw = hw0 + p;
    int h = hw / WW, w = hw % WW;
    float4 f = fields[pix0 + p];
    float sn = f.x, cs = f.y, rwr = f.z, wr = f.w;
    const u16* xbase = xt + (size_t)b*HWSZ*64;

    // mfma role
    int wd = t >> 6, lane = t & 63;
    int quad = lane >> 4, l15 = lane & 15;
    floatx4 acc[4];
#pragma unroll
    for (int i=0;i<4;i++) acc[i] = (floatx4){0.f,0.f,0.f,0.f};
    const short8* bfr = (const short8*)bfrag;

    u32 r00[8], r01[8], r10[8], r11[8];
    float w00, w01, w10, w11;

    auto coords_load = [&](int k) {
        int di = k/3 - 1;
        int dj = k%3 - 1;
        float bd0 = (float)di * rwr;
        float bd1 = (float)dj * wr;
        float py = (float)h + cs*bd0 + sn*bd1;
        float px = (float)w - sn*bd0 + cs*bd1;
        float y0f = floorf(py), x0f = floorf(px);
        float ty = py - y0f, tx = px - x0f;
        int y0 = (int)y0f, x0 = (int)x0f;
        int y1 = y0 + 1,   x1 = x0 + 1;
        float fy0 = ((unsigned)y0 < (unsigned)HH) ? 1.f : 0.f;
        float fy1 = ((unsigned)y1 < (unsigned)HH) ? 1.f : 0.f;
        float fx0 = ((unsigned)x0 < (unsigned)WW) ? 1.f : 0.f;
        float fx1 = ((unsigned)x1 < (unsigned)WW) ? 1.f : 0.f;
        int yc0 = min(max(y0,0),HH-1), yc1 = min(max(y1,0),HH-1);
        int xc0 = min(max(x0,0),WW-1), xc1 = min(max(x1,0),WW-1);
        w00 = (1.f-ty)*(1.f-tx)*fy0*fx0;
        w01 = (1.f-ty)*tx      *fy0*fx1;
        w10 = ty      *(1.f-tx)*fy1*fx0;
        w11 = ty      *tx      *fy1*fx1;
        const u16* row0 = xbase + (size_t)(yc0*WW)*64 + q*16;
        const u16* row1 = xbase + (size_t)(yc1*WW)*64 + q*16;
        load16(row0 + xc0*64, r00);
        load16(row0 + xc1*64, r01);
        load16(row1 + xc0*64, r10);
        load16(row1 + xc1*64, r11);
    };

    auto blend_store = [&](int buf) {
        u32 packed[8];
#pragma unroll
        for (int d=0; d<8; d++) {
            float s0 = w00*bflo(r00[d]) + w01*bflo(r01[d]) + w10*bflo(r10[d]) + w11*bflo(r11[d]);
            float s1 = w00*bfhi(r00[d]) + w01*bfhi(r01[d]) + w10*bfhi(r10[d]) + w11*bfhi(r11[d]);
            packed[d] = pkbf(s0, s1);
        }
        uint4* dst = (uint4*)&samp[buf][p*72 + q*16];
        dst[0] = make_uint4(packed[0],packed[1],packed[2],packed[3]);
        dst[1] = make_uint4(packed[4],packed[5],packed[6],packed[7]);
    };

    coords_load(0);
    blend_store(0);

#pragma unroll 1
    for (int k = 0; k < 9; k++) {
        __syncthreads();
        if (k < 8) coords_load(k+1);          // gathers in flight across MFMA phase
        short8 b0 = bfr[((k*2+0)*4 + wd)*64 + lane];
        short8 b1 = bfr[((k*2+1)*4 + wd)*64 + lane];
        const u16* sb = samp[k & 1];
#pragma unroll
        for (int mt=0; mt<4; mt++) {
            int pr = mt*16 + l15;
            short8 a0 = *(const short8*)&sb[pr*72 +      quad*8];
            short8 a1 = *(const short8*)&sb[pr*72 + 32 + quad*8];
            acc[mt] = __builtin_amdgcn_mfma_f32_16x16x32_bf16(a0, b0, acc[mt], 0, 0, 0);
            acc[mt] = __builtin_amdgcn_mfma_f32_16x16x32_bf16(a1, b1, acc[mt], 0, 0, 0);
        }
        if (k < 8) blend_store((k+1) & 1);
    }
    __syncthreads();   // tap 8 read samp[0]; epilogue reuses it

    // ---- epilogue: transpose acc through LDS, coalesced stores ----
    {
        int o = wd*16 + l15;
#pragma unroll
        for (int mt=0; mt<4; mt++)
#pragma unroll
            for (int rg=0; rg<4; rg++) {
                int pxi = mt*16 + quad*4 + rg;
                samp[0][o*72 + pxi] = f2bf(acc[mt][rg]);
            }
    }
    __syncthreads();
    {
        int o = t >> 2, q2 = t & 3;
        const uint4* s = (const uint4*)&samp[0][o*72 + q2*16];
        uint4 v0 = s[0], v1 = s[1];
        size_t base = (size_t)(b*64 + o)*HWSZ + hw0 + q2*16;
        if (fp32) {
            float4* df = (float4*)((float*)out + base);
            df[0] = make_float4(bflo(v0.x), bfhi(v0.x), bflo(v0.y), bfhi(v0.y));
            df[1] = make_float4(bflo(v0.z), bfhi(v0.z), bflo(v0.w), bfhi(v0.w));
            df[2] = make_float4(bflo(v1.x), bfhi(v1.x), bflo(v1.y), bfhi(v1.y));
            df[3] = make_float4(bflo(v1.z), bfhi(v1.z), bflo(v1.w), bfhi(v1.w));
        } else {
            uint4* du = (uint4*)((u16*)out + base);
            du[0] = v0; du[1] = v1;
        }
    }
}

extern "C" void kernel_launch(void* const* d_in, const int* in_sizes, int n_in,
                              void* d_out, int out_size, void* d_ws, size_t ws_size,
                              hipStream_t stream) {
    const void* x    = d_in[0];
    const void* wm   = d_in[1];
    const void* wrot = d_in[2];
    const void* brot = d_in[3];
    const void* wstr = d_in[4];
    const void* bstr = d_in[5];
    const void* wwh  = d_in[6];
    const void* bwh  = d_in[7];

    char* ws = (char*)d_ws;
    u16*    xt     = (u16*)   (ws);              // 9,437,184 B
    float4* fields = (float4*)(ws + 9437184);    // 1,179,648 B
    u16*    bfrag  = (u16*)   (ws + 10616832);   //    73,728 B
    float*  wf     = (float*) (ws + 10690560);   //    36,880 B (9220 floats)

    k0_prep  <<<dim3(144),   dim3(256), 0, stream>>>(x, wm, wrot, brot, wstr, bstr, wwh, bwh, bfrag, wf);
    k12_fused<<<dim3(NTILE), dim3(512), 0, stream>>>(x, wf, xt, fields);
    k3_main  <<<dim3(NTILE), dim3(256), 0, stream>>>(x, xt, (const float4*)fields, bfrag, d_out);
}

// Round 11
// 146.771 us; speedup vs baseline: 1.6944x; 1.0340x over previous
//
#include <hip/hip_runtime.h>
#include <hip/hip_bf16.h>
#include <stdint.h>

typedef unsigned short u16;
typedef unsigned int   u32;

#define HH 192
#define WW 192
#define HWSZ (192*192)
#define NPIX (2*HWSZ)
#define NTILE 1152          // 64-pixel tiles
#define TPB   144           // tiles per XCD band (NTILE/8)

typedef __attribute__((ext_vector_type(8))) short short8;
typedef __attribute__((ext_vector_type(4))) float floatx4;

__device__ __forceinline__ float bflo(u32 u){ union{u32 i; float f;} v; v.i = u<<16; return v.f; }
__device__ __forceinline__ float bfhi(u32 u){ union{u32 i; float f;} v; v.i = u & 0xffff0000u; return v.f; }
__device__ __forceinline__ float bf2f(u16 u){ union{u32 i; float f;} v; v.i = ((u32)u)<<16; return v.f; }
__device__ __forceinline__ u16 f2bf(float f){
    union{float f; u32 i;} v; v.f = f;
    u32 b = v.i;
    u32 r = b + 0x7fffu + ((b>>16)&1u);
    return (u16)(r>>16);
}
// packed f32x2 -> bf16x2 (v_cvt_pk_bf16_f32), RN-even same as f2bf
__device__ __forceinline__ u32 pkbf(float a, float b){
    __hip_bfloat162 h = __float22bfloat162_rn(make_float2(a, b));
    union { __hip_bfloat162 h; u32 u; } cv; cv.h = h; return cv.u;
}

// XCD band swizzle: round-robin dispatch => blk&7 is (assumed) XCD id;
// each XCD owns a contiguous band of 144 tiles (24 image rows) -> L2-resident.
__device__ __forceinline__ int band_tile(int blk){ return (blk & 7)*TPB + (blk >> 3); }

// ---- dtype sniffer: is x fp32 (vs bf16)? ----
__device__ __forceinline__ int sniff_fp32(const void* x) {
    const u32* x32 = (const u32*)x;
    int l = threadIdx.x & 63;
    u32 v = x32[l*2];
    u32 e = (v >> 7) & 0xFFu;
    int vote = (e >= 0x60u && e <= 0x8Fu) ? 1 : 0;
    unsigned long long m = __ballot(vote);
    return (__popcll(m) < 40) ? 1 : 0;
}

__device__ __forceinline__ u16 pick16(const void* p, int i, int fp32) {
    return fp32 ? f2bf(((const float*)p)[i]) : ((const u16*)p)[i];
}
__device__ __forceinline__ float pickf(const void* p, int i, int fp32) {
    return fp32 ? ((const float*)p)[i] : bf2f(((const u16*)p)[i]);
}

// ---------------- K0: weight prep ----------------
__global__ __launch_bounds__(256) void k0_prep(const void* __restrict__ x,
                        const void* __restrict__ wm,
                        const void* __restrict__ wrot,
                        const void* __restrict__ brot,
                        const void* __restrict__ wstr,
                        const void* __restrict__ bstr,
                        const void* __restrict__ wwh,
                        const void* __restrict__ bwh,
                        u16* __restrict__ bfrag, float* __restrict__ wf) {
    int fp32 = sniff_fp32(x);
    int e = blockIdx.x*256 + threadIdx.x;
    if (e < 9*2*4*64*8) {
        int j    = e & 7;
        int lane = (e>>3) & 63;
        int wd   = (e>>9) & 3;
        int kk   = (e>>11) & 1;
        int k    = e>>12;
        int o = wd*16 + (lane & 15);
        int c = kk*32 + ((lane>>4)&3)*8 + j;
        bfrag[e] = pick16(wm, (o*64 + c)*9 + k, fp32);
    }
    if (e < 9216) {               // e = (c*9+tap)*4 + j
        int j   = e & 3;
        int rem = e >> 2;
        int tap = rem % 9;
        int c   = rem / 9;
        float s;
        if (j==0)      s = pickf(wrot, c*9 + tap, fp32);
        else if (j==1) s = pickf(wrot, (64+c)*9 + tap, fp32);
        else if (j==2) s = pickf(wstr, c*9 + tap, fp32);
        else           s = pickf(wwh,  c*9 + tap, fp32);
        wf[e] = s;
    }
    if (e < 4) {
        float bv;
        if (e==0)      bv = pickf(brot, 0, fp32);
        else if (e==1) bv = pickf(brot, 1, fp32);
        else if (e==2) bv = pickf(bstr, 0, fp32);
        else           bv = pickf(bwh,  0, fp32);
        wf[9216 + e] = bv;
    }
}

// ---------------- K12: FUSED transpose + field convs, high-MLP stencil ----------------
// 512 threads: wave q (0..7) covers channels q*8..q*8+7 of a 64-pixel tile.
// Offsets/masks hoisted per pixel; per channel all 9 loads issue before FMAs.
// Center tap = v[4] (mask==1 by construction) -> packed into the xt write.
// Everything fully unrolled: register indices all compile-time.
__global__ __launch_bounds__(512) void k12_fused(const void* __restrict__ x, const float* __restrict__ wf,
                          u16* __restrict__ xt, float4* __restrict__ fields) {
    __shared__ float4 red[512];
    int fp32 = sniff_fp32(x);
    int t = threadIdx.x;
    int q = t >> 6, p = t & 63;       // q: 8-channel group
    int gp0 = band_tile(blockIdx.x) * 64;
    int gp = gp0 + p;
    int b = gp / HWSZ, hw = gp % HWSZ;
    int h = hw / WW, w = hw % WW;

    int   offs[9];
    float msks[9];
#pragma unroll
    for (int kh = 0; kh < 3; kh++) {
        int y   = h + kh - 1;
        int yok = ((unsigned)y < (unsigned)HH) ? 1 : 0;
        int yc  = min(max(y,0),HH-1);
#pragma unroll
        for (int kw = 0; kw < 3; kw++) {
            int xx  = w + kw - 1;
            int xok = ((unsigned)xx < (unsigned)WW) ? 1 : 0;
            offs[kh*3+kw] = yc*WW + min(max(xx,0),WW-1);
            msks[kh*3+kw] = (yok & xok) ? 1.0f : 0.0f;
        }
    }

    float a0=0.f, a1=0.f, a2=0.f, a3=0.f;
    u32 xtv0, xtv1, xtv2, xtv3;
    const float4* wrow = (const float4*)wf + (size_t)q*8*9;
    if (fp32) {
        const float* xp = (const float*)x + (size_t)(b*64 + q*8)*HWSZ;
        float vc[8];
#pragma unroll
        for (int c8 = 0; c8 < 8; c8++) {
            const float* pl = xp + (size_t)c8*HWSZ;
            float v[9];
#pragma unroll
            for (int i = 0; i < 9; i++) v[i] = pl[offs[i]];   // 9 independent loads
            vc[c8] = v[4];                                    // center tap
#pragma unroll
            for (int i = 0; i < 9; i++) {
                float vv = v[i] * msks[i];
                float4 wv = wrow[c8*9 + i];
                a0 = fmaf(vv, wv.x, a0);
                a1 = fmaf(vv, wv.y, a1);
                a2 = fmaf(vv, wv.z, a2);
                a3 = fmaf(vv, wv.w, a3);
            }
        }
        xtv0 = pkbf(vc[0], vc[1]);
        xtv1 = pkbf(vc[2], vc[3]);
        xtv2 = pkbf(vc[4], vc[5]);
        xtv3 = pkbf(vc[6], vc[7]);
    } else {
        const u16* xp = (const u16*)x + (size_t)(b*64 + q*8)*HWSZ;
        u32 vc[8];
#pragma unroll
        for (int c8 = 0; c8 < 8; c8++) {
            const u16* pl = xp + (size_t)c8*HWSZ;
            u32 v[9];
#pragma unroll
            for (int i = 0; i < 9; i++) v[i] = pl[offs[i]];
            vc[c8] = v[4];
#pragma unroll
            for (int i = 0; i < 9; i++) {
                float vv = bf2f((u16)v[i]) * msks[i];
                float4 wv = wrow[c8*9 + i];
                a0 = fmaf(vv, wv.x, a0);
                a1 = fmaf(vv, wv.y, a1);
                a2 = fmaf(vv, wv.z, a2);
                a3 = fmaf(vv, wv.w, a3);
            }
        }
        xtv0 = vc[0] | (vc[1]<<16);
        xtv1 = vc[2] | (vc[3]<<16);
        xtv2 = vc[4] | (vc[5]<<16);
        xtv3 = vc[6] | (vc[7]<<16);
    }
    // xt write: 8 channels (16 B) of pixel gp
    *(uint4*)(xt + (size_t)gp*64 + q*8) = make_uint4(xtv0, xtv1, xtv2, xtv3);

    // fields reduce: 512 -> 64
    red[t] = make_float4(a0, a1, a2, a3);
    __syncthreads();
    if (t < 64) {
        float s0 = 0.f, s1 = 0.f, s2 = 0.f, s3 = 0.f;
#pragma unroll
        for (int j = 0; j < 8; j++) {
            float4 r = red[t + 64*j];
            s0 += r.x; s1 += r.y; s2 += r.z; s3 += r.w;
        }
        float sr = s0 + wf[9216];
        float cr = s1 + wf[9217];
        float inv = 1.0f / sqrtf(sr*sr + cr*cr + 1e-6f);
        float r  = tanhf(s2 + wf[9218])*1.25f + 1.75f;
        float wrv = 1.0f + fmaxf(s3 + wf[9219], 0.0f);
        fields[gp0 + t] = make_float4(sr*inv, cr*inv, r*wrv, wrv);
    }
}

// ---------------- K3: sample + MFMA GEMM, double-buffered LDS, band swizzle ----------------
// (proven version — unchanged)
__device__ __forceinline__ void load16(const u16* base, u32 r[8]) {
    const uint4* p = (const uint4*)base;
    uint4 a = p[0], b = p[1];
    r[0]=a.x; r[1]=a.y; r[2]=a.z; r[3]=a.w;
    r[4]=b.x; r[5]=b.y; r[6]=b.z; r[7]=b.w;
}

__global__ __launch_bounds__(256) void k3_main(const void* __restrict__ xorig,
                                               const u16* __restrict__ xt,
                                               const float4* __restrict__ fields,
                                               const u16* __restrict__ bfrag,
                                               void* __restrict__ out) {
    __shared__ u16 samp[2][64*72];   // double buffer: 64 px x 64 ch, rows padded to 72

    int fp32 = sniff_fp32(xorig);
    int t = threadIdx.x;
    int pix0 = band_tile(blockIdx.x) * 64;
    int b   = pix0 / HWSZ;
    int hw0 = pix0 % HWSZ;

    // sampling role
    int p = t >> 2, q = t & 3;            // pixel in tile, 16-ch chunk
    int hw = hw0 + p;
    int h = hw / WW, w = hw % WW;
    float4 f = fields[pix0 + p];
    float sn = f.x, cs = f.y, rwr = f.z, wr = f.w;
    const u16* xbase = xt + (size_t)b*HWSZ*64;

    // mfma role
    int wd = t >> 6, lane = t & 63;
    int quad = lane >> 4, l15 = lane & 15;
    floatx4 acc[4];
#pragma unroll
    for (int i=0;i<4;i++) acc[i] = (floatx4){0.f,0.f,0.f,0.f};
    const short8* bfr = (const short8*)bfrag;

    u32 r00[8], r01[8], r10[8], r11[8];
    float w00, w01, w10, w11;

    auto coords_load = [&](int k) {
        int di = k/3 - 1;
        int dj = k%3 - 1;
        float bd0 = (float)di * rwr;
        float bd1 = (float)dj * wr;
        float py = (float)h + cs*bd0 + sn*bd1;
        float px = (float)w - sn*bd0 + cs*bd1;
        float y0f = floorf(py), x0f = floorf(px);
        float ty = py - y0f, tx = px - x0f;
        int y0 = (int)y0f, x0 = (int)x0f;
        int y1 = y0 + 1,   x1 = x0 + 1;
        float fy0 = ((unsigned)y0 < (unsigned)HH) ? 1.f : 0.f;
        float fy1 = ((unsigned)y1 < (unsigned)HH) ? 1.f : 0.f;
        float fx0 = ((unsigned)x0 < (unsigned)WW) ? 1.f : 0.f;
        float fx1 = ((unsigned)x1 < (unsigned)WW) ? 1.f : 0.f;
        int yc0 = min(max(y0,0),HH-1), yc1 = min(max(y1,0),HH-1);
        int xc0 = min(max(x0,0),WW-1), xc1 = min(max(x1,0),WW-1);
        w00 = (1.f-ty)*(1.f-tx)*fy0*fx0;
        w01 = (1.f-ty)*tx      *fy0*fx1;
        w10 = ty      *(1.f-tx)*fy1*fx0;
        w11 = ty      *tx      *fy1*fx1;
        const u16* row0 = xbase + (size_t)(yc0*WW)*64 + q*16;
        const u16* row1 = xbase + (size_t)(yc1*WW)*64 + q*16;
        load16(row0 + xc0*64, r00);
        load16(row0 + xc1*64, r01);
        load16(row1 + xc0*64, r10);
        load16(row1 + xc1*64, r11);
    };

    auto blend_store = [&](int buf) {
        u32 packed[8];
#pragma unroll
        for (int d=0; d<8; d++) {
            float s0 = w00*bflo(r00[d]) + w01*bflo(r01[d]) + w10*bflo(r10[d]) + w11*bflo(r11[d]);
            float s1 = w00*bfhi(r00[d]) + w01*bfhi(r01[d]) + w10*bfhi(r10[d]) + w11*bfhi(r11[d]);
            packed[d] = pkbf(s0, s1);
        }
        uint4* dst = (uint4*)&samp[buf][p*72 + q*16];
        dst[0] = make_uint4(packed[0],packed[1],packed[2],packed[3]);
        dst[1] = make_uint4(packed[4],packed[5],packed[6],packed[7]);
    };

    coords_load(0);
    blend_store(0);

#pragma unroll 1
    for (int k = 0; k < 9; k++) {
        __syncthreads();
        if (k < 8) coords_load(k+1);          // gathers in flight across MFMA phase
        short8 b0 = bfr[((k*2+0)*4 + wd)*64 + lane];
        short8 b1 = bfr[((k*2+1)*4 + wd)*64 + lane];
        const u16* sb = samp[k & 1];
#pragma unroll
        for (int mt=0; mt<4; mt++) {
            int pr = mt*16 + l15;
            short8 a0 = *(const short8*)&sb[pr*72 +      quad*8];
            short8 a1 = *(const short8*)&sb[pr*72 + 32 + quad*8];
            acc[mt] = __builtin_amdgcn_mfma_f32_16x16x32_bf16(a0, b0, acc[mt], 0, 0, 0);
            acc[mt] = __builtin_amdgcn_mfma_f32_16x16x32_bf16(a1, b1, acc[mt], 0, 0, 0);
        }
        if (k < 8) blend_store((k+1) & 1);
    }
    __syncthreads();   // tap 8 read samp[0]; epilogue reuses it

    // ---- epilogue: transpose acc through LDS, coalesced stores ----
    {
        int o = wd*16 + l15;
#pragma unroll
        for (int mt=0; mt<4; mt++)
#pragma unroll
            for (int rg=0; rg<4; rg++) {
                int pxi = mt*16 + quad*4 + rg;
                samp[0][o*72 + pxi] = f2bf(acc[mt][rg]);
            }
    }
    __syncthreads();
    {
        int o = t >> 2, q2 = t & 3;
        const uint4* s = (const uint4*)&samp[0][o*72 + q2*16];
        uint4 v0 = s[0], v1 = s[1];
        size_t base = (size_t)(b*64 + o)*HWSZ + hw0 + q2*16;
        if (fp32) {
            float4* df = (float4*)((float*)out + base);
            df[0] = make_float4(bflo(v0.x), bfhi(v0.x), bflo(v0.y), bfhi(v0.y));
            df[1] = make_float4(bflo(v0.z), bfhi(v0.z), bflo(v0.w), bfhi(v0.w));
            df[2] = make_float4(bflo(v1.x), bfhi(v1.x), bflo(v1.y), bfhi(v1.y));
            df[3] = make_float4(bflo(v1.z), bfhi(v1.z), bflo(v1.w), bfhi(v1.w));
        } else {
            uint4* du = (uint4*)((u16*)out + base);
            du[0] = v0; du[1] = v1;
        }
    }
}

extern "C" void kernel_launch(void* const* d_in, const int* in_sizes, int n_in,
                              void* d_out, int out_size, void* d_ws, size_t ws_size,
                              hipStream_t stream) {
    const void* x    = d_in[0];
    const void* wm   = d_in[1];
    const void* wrot = d_in[2];
    const void* brot = d_in[3];
    const void* wstr = d_in[4];
    const void* bstr = d_in[5];
    const void* wwh  = d_in[6];
    const void* bwh  = d_in[7];

    char* ws = (char*)d_ws;
    u16*    xt     = (u16*)   (ws);              // 9,437,184 B
    float4* fields = (float4*)(ws + 9437184);    // 1,179,648 B
    u16*    bfrag  = (u16*)   (ws + 10616832);   //    73,728 B
    float*  wf     = (float*) (ws + 10690560);   //    36,880 B (9220 floats)

    k0_prep  <<<dim3(144),   dim3(256), 0, stream>>>(x, wm, wrot, brot, wstr, bstr, wwh, bwh, bfrag, wf);
    k12_fused<<<dim3(NTILE), dim3(512), 0, stream>>>(x, wf, xt, fields);
    k3_main  <<<dim3(NTILE), dim3(256), 0, stream>>>(x, xt, (const float4*)fields, bfrag, d_out);
}